// Round 10
// baseline (460.747 us; speedup 1.0000x reference)
//
#include <hip/hip_runtime.h>
#include <hip/hip_bf16.h>
#include <stdint.h>

#define NN 8192
#define DD 1024

typedef __attribute__((ext_vector_type(4))) float f32x4;
typedef __attribute__((ext_vector_type(16))) float f32x16;
typedef __attribute__((ext_vector_type(8))) short bf16x8;
using bf16_t = __hip_bfloat16;

__device__ __forceinline__ void gload16(const void* g, void* l) {
  __builtin_amdgcn_global_load_lds(
      (const __attribute__((address_space(1))) void*)g,
      (__attribute__((address_space(3))) void*)l, 16, 0, 0);
}
__device__ __forceinline__ int imin(int a, int b) { return a < b ? a : b; }

// ---------------- cast fp32 -> bf16, 8 elems/thread ----------------
__global__ __launch_bounds__(256) void cast_bf16_kernel(
    const float* __restrict__ in, bf16_t* __restrict__ out, int n8) {
  int i = blockIdx.x * 256 + threadIdx.x;
  if (i >= n8) return;
  const float4* p4 = (const float4*)in + (size_t)i * 2;
  float4 a = p4[0], b = p4[1];
  __align__(16) bf16_t tmp[8];
  tmp[0] = __float2bfloat16(a.x); tmp[1] = __float2bfloat16(a.y);
  tmp[2] = __float2bfloat16(a.z); tmp[3] = __float2bfloat16(a.w);
  tmp[4] = __float2bfloat16(b.x); tmp[5] = __float2bfloat16(b.y);
  tmp[6] = __float2bfloat16(b.z); tmp[7] = __float2bfloat16(b.w);
  *((uint4*)out + i) = *(const uint4*)tmp;
}

// ---------------- 128^2 m97-structure NT GEMM (projections only) ----------------
template<int MODE>
__global__ __launch_bounds__(256, 2)
void gemm_bt(const bf16_t* __restrict__ A, const bf16_t* __restrict__ B,
             const float* __restrict__ bias, void* __restrict__ Cout,
             int M, int Nc, int K, int ldc, float scale, int nbx) {
  __shared__ bf16_t As[128 * 32];
  __shared__ bf16_t Bs[128 * 32];
  const int t = threadIdx.x;
  const int nwg = gridDim.x;
  const int bid = (blockIdx.x & 7) * (nwg >> 3) + (blockIdx.x >> 3);
  const int bm = bid / nbx, bn = bid % nbx;
  const int lane = t & 63, wave = t >> 6;
  const int wr = wave >> 1, wc = wave & 1;

  const int c0 = t, c1 = t + 256;
  const bf16_t* ag0 = A + (size_t)(bm * 128 + (c0 >> 2)) * K + (c0 & 3) * 8;
  const bf16_t* ag1 = A + (size_t)(bm * 128 + (c1 >> 2)) * K + (c1 & 3) * 8;
  const bf16_t* bg0 = B + (size_t)(bn * 128 + (c0 >> 2)) * K + (c0 & 3) * 8;
  const bf16_t* bg1 = B + (size_t)(bn * 128 + (c1 >> 2)) * K + (c1 & 3) * 8;
  bf16_t* la0 = As + c0 * 8;
  bf16_t* la1 = As + c1 * 8;
  bf16_t* lb0 = Bs + c0 * 8;
  bf16_t* lb1 = Bs + c1 * 8;

  f32x4 acc[4][4] = {};
  const int fr = lane & 15;
  const int ko = (lane >> 4) * 8;

  for (int kt = 0; kt < K; kt += 32) {
    gload16(ag0 + kt, la0);
    gload16(ag1 + kt, la1);
    gload16(bg0 + kt, lb0);
    gload16(bg1 + kt, lb1);
    __syncthreads();
    bf16x8 af[4], bfv[4];
#pragma unroll
    for (int m = 0; m < 4; m++)
      af[m] = *(const bf16x8*)&As[(wr * 64 + m * 16 + fr) * 32 + ko];
#pragma unroll
    for (int n = 0; n < 4; n++)
      bfv[n] = *(const bf16x8*)&Bs[(wc * 64 + n * 16 + fr) * 32 + ko];
#pragma unroll
    for (int m = 0; m < 4; m++)
#pragma unroll
      for (int n = 0; n < 4; n++)
        acc[m][n] = __builtin_amdgcn_mfma_f32_16x16x32_bf16(af[m], bfv[n], acc[m][n], 0, 0, 0);
    __syncthreads();
  }

  const int rb = (lane >> 4) * 4;
#pragma unroll
  for (int m = 0; m < 4; m++) {
#pragma unroll
    for (int n = 0; n < 4; n++) {
      const int col = bn * 128 + wc * 64 + n * 16 + fr;
      const int row0 = bm * 128 + wr * 64 + m * 16 + rb;
      if (MODE == 0) {
        bf16_t* C = (bf16_t*)Cout;
        const float bv = bias[col];
#pragma unroll
        for (int j = 0; j < 4; j++)
          C[(size_t)(row0 + j) * ldc + col] = __float2bfloat16((acc[m][n][j] + bv) * scale);
      } else {
        bf16_t* C = (bf16_t*)Cout;
        const float bv = bias[col];
        __align__(8) bf16_t tmp[4];
#pragma unroll
        for (int j = 0; j < 4; j++)
          tmp[j] = __float2bfloat16((acc[m][n][j] + bv) * scale);
        *(ushort4*)&C[(size_t)col * ldc + row0] = *(const ushort4*)tmp;
      }
    }
  }
}

// ---------------- 256^2 NT GEMM with 32x32x16 MFMA ----------------
// Same staging/swizzle/barrier/vmcnt structure as R8 (all verified); only the
// compute side changes: 32 MFMA/wave/K-tile (4x fewer instructions, +20% pipe
// ceiling per m119) instead of 128.  Per-wave output 128x64 = 4x2 frags of
// 32x32, acc = 8 x f32x16 = 128 regs (AGPR).  A/B frag: row=lane&31,
// ko=(lane>>5)*8 ; C/D: col=lane&31, row=(reg&3)+8*(reg>>2)+4*(lane>>5).
// Read chunk (16B) within 128B row = ks*2 + (lane>>5), swizzled ^ (row&7)
// -> uniform 8 words/bank (port-optimal), staging swizzle unchanged.
template<int MODE>
__global__ __launch_bounds__(512, 2)
void gemm256(const bf16_t* __restrict__ A, int lda,
             const bf16_t* __restrict__ B, int ldb,
             void* __restrict__ Cout, int ldc,
             float* __restrict__ aux, int ksplit, int nkt, int nbx, int Mrows) {
  __shared__ char smem_raw[131072];
  const int t = threadIdx.x;
  const int nwg = gridDim.x;
  const int bid = (blockIdx.x & 7) * (nwg >> 3) + (blockIdx.x >> 3);
  const int bm = bid / nbx, bn = bid % nbx;
  const int lane = t & 63, wave = t >> 6;
  const int wr = wave >> 2, wc = wave & 3;   // 2M x 4N waves
  const int l31 = lane & 31, hi2 = lane >> 5;
  const int k0 = blockIdx.y * ksplit;

  // inverse-swizzled global source (linear gload_lds dest): chunk ^= row&7
  const int cswz = ((t & 7) ^ ((t >> 3) & 7)) * 8;  // elements
  uint32_t offA[2][2], offB[2][2];
#pragma unroll
  for (int h = 0; h < 2; h++)
#pragma unroll
    for (int l = 0; l < 2; l++) {
      const int r = h * 128 + l * 64 + (t >> 3);
      offA[h][l] = (uint32_t)((bm * 256 + r) * lda + k0 + cswz);
      offB[h][l] = (uint32_t)((bn * 256 + r) * ldb + k0 + cswz);
    }

  // swizzled ds_read bases: row-major [256][64] bf16 per operand region.
  // byte = row*128 + phys_chunk*16, phys_chunk = (ks*2 + hi2) ^ (row&7)
  const int e8 = l31 & 7;
  const int rA0 = (wr * 128 + l31) * 128;           // A row base (mf adds 32 rows)
  const int rB0 = 32768 + (wc * 64 + l31) * 128;    // B col base (nf adds 32 rows)
  int ck[4];
#pragma unroll
  for (int ks = 0; ks < 4; ks++) ck[ks] = (((ks * 2 + hi2) ^ e8) << 4);

  f32x16 acc[4][2] = {};
  bf16x8 af[4], bfv[2][4];

#define STA(buf, h, kt)                                                        \
  gload16(A + offA[h][0] + (size_t)(kt) * 64,                                  \
          smem_raw + (buf) * 65536 + (h) * 16384 + t * 16);                    \
  gload16(A + offA[h][1] + (size_t)(kt) * 64,                                  \
          smem_raw + (buf) * 65536 + (h) * 16384 + 8192 + t * 16);
#define STB(buf, h, kt)                                                        \
  gload16(B + offB[h][0] + (size_t)(kt) * 64,                                  \
          smem_raw + (buf) * 65536 + 32768 + (h) * 16384 + t * 16);            \
  gload16(B + offB[h][1] + (size_t)(kt) * 64,                                  \
          smem_raw + (buf) * 65536 + 32768 + (h) * 16384 + 8192 + t * 16);
#define RDA32(buf, mf, ks)                                                     \
  (*(const bf16x8*)(smem_raw + (buf) * 65536 + rA0 + (mf) * 4096 + ck[ks]))
#define RDB32(buf, nf, ks)                                                     \
  (*(const bf16x8*)(smem_raw + (buf) * 65536 + rB0 + (nf) * 4096 + ck[ks]))
#define MFMAK(buf, ks)                                                         \
  af[0] = RDA32(buf, 0, ks); af[1] = RDA32(buf, 1, ks);                        \
  af[2] = RDA32(buf, 2, ks); af[3] = RDA32(buf, 3, ks);                        \
  __builtin_amdgcn_s_setprio(1);                                               \
  _Pragma("unroll") for (int mf = 0; mf < 4; mf++)                             \
  _Pragma("unroll") for (int nf = 0; nf < 2; nf++)                             \
    acc[mf][nf] = __builtin_amdgcn_mfma_f32_32x32x16_bf16(                     \
        af[mf], bfv[nf][ks], acc[mf][nf], 0, 0, 0);                            \
  __builtin_amdgcn_s_setprio(0);

  // prologue: stage tile0 (buf0) fully + B of tile1 (buf1)
  STB(0, 0, 0) STB(0, 1, 0) STA(0, 0, 0) STA(0, 1, 0)
  STB(1, 0, 1) STB(1, 1, 1)
  asm volatile("s_waitcnt vmcnt(4)" ::: "memory");
  __builtin_amdgcn_s_barrier();

  const int nit = nkt >> 1;
  for (int it = 0; it < nit; ++it) {
    const int T1 = 2 * it + 1;
    const int s2 = imin(2 * it + 2, nkt - 1);
    const int s3 = imin(2 * it + 3, nkt - 1);

#define TILE32(buf, S1, S2, S3, S4)                                            \
    /* all B reads up front (8), then ks0 A + MFMA ks0 */                      \
    bfv[0][0] = RDB32(buf, 0, 0); bfv[1][0] = RDB32(buf, 1, 0);                \
    bfv[0][1] = RDB32(buf, 0, 1); bfv[1][1] = RDB32(buf, 1, 1);                \
    bfv[0][2] = RDB32(buf, 0, 2); bfv[1][2] = RDB32(buf, 1, 2);                \
    bfv[0][3] = RDB32(buf, 0, 3); bfv[1][3] = RDB32(buf, 1, 3);                \
    MFMAK(buf, 0)                                                              \
    /* MFMA ks0 issued => all B reads drained (in-order lgkm) for every wave */\
    __builtin_amdgcn_s_barrier();                                              \
    S1 S2 S3 S4                                                                \
    MFMAK(buf, 1)                                                              \
    MFMAK(buf, 2)                                                              \
    MFMAK(buf, 3)                                                              \
    asm volatile("s_waitcnt vmcnt(4)" ::: "memory");                           \
    __builtin_amdgcn_s_barrier();

    // tile on buf0 (T0); stages: buf1.A(T1), buf0.B(s2)
    TILE32(0, STA(1, 0, T1), STA(1, 1, T1), STB(0, 0, s2), STB(0, 1, s2))
    // tile on buf1 (T1); stages: buf0.A(s2), buf1.B(s3)
    TILE32(1, STA(0, 0, s2), STA(0, 1, s2), STB(1, 0, s3), STB(1, 1, s3))
#undef TILE32
  }

  // drain stray clamped stages before reusing/leaving LDS
  asm volatile("s_waitcnt vmcnt(0)" ::: "memory");
  __builtin_amdgcn_s_barrier();

  const int gc0 = bn * 256 + wc * 64 + l31;

  if (MODE == 3) {
    float* rsum = (float*)smem_raw;
    if (t < 256) rsum[t] = 0.f;
    __syncthreads();
    bf16_t* C = (bf16_t*)Cout;
#pragma unroll
    for (int mf = 0; mf < 4; mf++) {
#pragma unroll
      for (int reg = 0; reg < 16; reg++) {
        const int lrow = wr * 128 + mf * 32 + (reg & 3) + 8 * (reg >> 2) + 4 * hi2;
        const int grow = bm * 256 + lrow;
        float rs = 0.f;
#pragma unroll
        for (int nf = 0; nf < 2; nf++) {
          float e2 = exp2f(acc[mf][nf][reg] * 1.44269504088896f);
          bf16_t pb = __float2bfloat16(e2);
          C[(size_t)grow * ldc + gc0 + nf * 32] = pb;
          rs += __bfloat162float(pb);
        }
        rs += __shfl_xor(rs, 1); rs += __shfl_xor(rs, 2);
        rs += __shfl_xor(rs, 4); rs += __shfl_xor(rs, 8);
        rs += __shfl_xor(rs, 16);
        if (l31 == 0) atomicAdd(&rsum[lrow], rs);
      }
    }
    __syncthreads();
    if (t < 256) aux[(size_t)bn * Mrows + bm * 256 + t] = rsum[t];
  } else {  // MODE 4: raw fp32 partial; y=0 -> Cout, y=1 -> aux
    float* C = blockIdx.y == 0 ? (float*)Cout : aux;
#pragma unroll
    for (int mf = 0; mf < 4; mf++)
#pragma unroll
      for (int reg = 0; reg < 16; reg++) {
        const int grow = bm * 256 + wr * 128 + mf * 32 + (reg & 3) + 8 * (reg >> 2) + 4 * hi2;
#pragma unroll
        for (int nf = 0; nf < 2; nf++)
          C[(size_t)grow * ldc + gc0 + nf * 32] = acc[mf][nf][reg];
      }
  }
#undef STA
#undef STB
#undef RDA32
#undef RDB32
#undef MFMAK
}

// ---------------- rowsum partials -> 1/l ----------------
__global__ __launch_bounds__(256) void rowsum_inv_kernel(
    const float* __restrict__ partial, float* __restrict__ inv_l, int nb) {
  const int r = blockIdx.x * 256 + threadIdx.x;
  float s = 0.f;
  for (int b = 0; b < nb; b++) s += partial[(size_t)b * NN + r];
  inv_l[r] = 1.f / s;
}

// ---------------- out = (out + o1) * inv_l[row] ----------------
__global__ __launch_bounds__(256) void combine_kernel(
    float* __restrict__ out, const float* __restrict__ o1,
    const float* __restrict__ inv_l) {
  const size_t i = (size_t)blockIdx.x * 256 + threadIdx.x;  // float4 index
  const float s = inv_l[(int)((i * 4) >> 10)];
  float4 a = ((const float4*)out)[i];
  const float4 b = ((const float4*)o1)[i];
  a.x = (a.x + b.x) * s; a.y = (a.y + b.y) * s;
  a.z = (a.z + b.z) * s; a.w = (a.w + b.w) * s;
  ((float4*)out)[i] = a;
}

extern "C" void kernel_launch(void* const* d_in, const int* in_sizes, int n_in,
                              void* d_out, int out_size, void* d_ws, size_t ws_size,
                              hipStream_t stream) {
  const float* queries = (const float*)d_in[0];
  const float* key_in  = (const float*)d_in[1];
  const float* values  = (const float*)d_in[2];
  const float* Wq = (const float*)d_in[3];
  const float* bq = (const float*)d_in[4];
  const float* Wk = (const float*)d_in[5];
  const float* bk = (const float*)d_in[6];
  const float* Wv = (const float*)d_in[7];
  const float* bv = (const float*)d_in[8];
  float* out = (float*)d_out;
  char* ws = (char*)d_ws;

  const size_t MB = 1024 * 1024;
  bf16_t* qb = (bf16_t*)(ws);                 // 16 MiB
  bf16_t* kb = (bf16_t*)(ws + 16 * MB);       // 16 MiB
  bf16_t* vT = (bf16_t*)(ws + 32 * MB);       // [1024][8192], 16 MiB
  bf16_t* P  = (bf16_t*)(ws + 48 * MB);       // [8192][8192] bf16, 128 MiB
  float* partial = (float*)(ws + 176 * MB);   // [32][8192] fp32, 1 MiB
  float* inv_l   = (float*)(ws + 177 * MB);   // 32 KiB
  float* o1      = (float*)(ws + 178 * MB);   // [8192][1024] fp32, 32 MiB
  bf16_t* xb = (bf16_t*)(ws + 48 * MB);       // staging (projection phase only)
  bf16_t* wb = (bf16_t*)(ws + 64 * MB);

  const int nd8 = NN * DD / 8, dd8 = DD * DD / 8;

  // q = (queries @ Wq^T + bq) * (1/sqrt(D))
  cast_bf16_kernel<<<nd8 / 256, 256, 0, stream>>>(queries, xb, nd8);
  cast_bf16_kernel<<<dd8 / 256, 256, 0, stream>>>(Wq, wb, dd8);
  gemm_bt<0><<<(NN / 128) * (DD / 128), 256, 0, stream>>>(
      xb, wb, bq, qb, NN, DD, DD, DD, 0.03125f, DD / 128);
  // k = key @ Wk^T + bk
  cast_bf16_kernel<<<nd8 / 256, 256, 0, stream>>>(key_in, xb, nd8);
  cast_bf16_kernel<<<dd8 / 256, 256, 0, stream>>>(Wk, wb, dd8);
  gemm_bt<0><<<(NN / 128) * (DD / 128), 256, 0, stream>>>(
      xb, wb, bk, kb, NN, DD, DD, DD, 1.0f, DD / 128);
  // vT = (values @ Wv^T + bv)^T
  cast_bf16_kernel<<<nd8 / 256, 256, 0, stream>>>(values, xb, nd8);
  cast_bf16_kernel<<<dd8 / 256, 256, 0, stream>>>(Wv, wb, dd8);
  gemm_bt<1><<<(NN / 128) * (DD / 128), 256, 0, stream>>>(
      xb, wb, bv, vT, NN, DD, DD, NN, 1.0f, DD / 128);

  // fused QK^T -> exp -> bf16 P (+ partial row sums)
  gemm256<3><<<dim3((NN / 256) * (NN / 256)), 512, 0, stream>>>(
      qb, DD, kb, DD, P, NN, partial, 0, DD / 64, NN / 256, NN);
  rowsum_inv_kernel<<<NN / 256, 256, 0, stream>>>(partial, inv_l, NN / 256);
  // PV split-K=2: y=0 -> out (raw), y=1 -> o1 (raw)
  gemm256<4><<<dim3((NN / 256) * (DD / 256), 2), 512, 0, stream>>>(
      P, NN, vT, NN, out, DD, o1, NN / 2, NN / 2 / 64, DD / 256, NN);
  // out = (out + o1) * inv_l[row]
  combine_kernel<<<NN * DD / 4 / 256, 256, 0, stream>>>(out, o1, inv_l);
}

// Round 12
// 401.432 us; speedup vs baseline: 1.1478x; 1.1478x over previous
//
#include <hip/hip_runtime.h>
#include <hip/hip_bf16.h>
#include <stdint.h>

#define NN 8192
#define DD 1024

typedef __attribute__((ext_vector_type(4))) float f32x4;
typedef __attribute__((ext_vector_type(8))) short bf16x8;
using bf16_t = __hip_bfloat16;

__device__ __forceinline__ void gload16(const void* g, void* l) {
  __builtin_amdgcn_global_load_lds(
      (const __attribute__((address_space(1))) void*)g,
      (__attribute__((address_space(3))) void*)l, 16, 0, 0);
}
__device__ __forceinline__ int imin(int a, int b) { return a < b ? a : b; }

// ---------------- batched cast fp32 -> bf16 (all 3 inputs + 3 weights) -------
// regions: out_x = 3 x nd8 chunks (q,k,v inputs), out_w = 3 x dd8 (Wq,Wk,Wv)
__global__ __launch_bounds__(256) void cast6_kernel(
    const float* __restrict__ i0, const float* __restrict__ i1,
    const float* __restrict__ i2, const float* __restrict__ w0,
    const float* __restrict__ w1, const float* __restrict__ w2,
    bf16_t* __restrict__ out_x, bf16_t* __restrict__ out_w) {
  const int nd8 = NN * DD / 8;   // 1<<20
  const int dd8 = DD * DD / 8;   // 1<<17
  int i = blockIdx.x * 256 + threadIdx.x;
  const float* src;
  bf16_t* dst;
  if (i < 3 * nd8) {
    const int r = i >> 20, j = i & (nd8 - 1);
    src = (r == 0 ? i0 : r == 1 ? i1 : i2) + (size_t)j * 8;
    dst = out_x + (size_t)i * 8;
  } else {
    const int k = i - 3 * nd8;
    const int r = k >> 17, j = k & (dd8 - 1);
    src = (r == 0 ? w0 : r == 1 ? w1 : w2) + (size_t)j * 8;
    dst = out_w + (size_t)k * 8;
  }
  const float4 a = ((const float4*)src)[0], b = ((const float4*)src)[1];
  __align__(16) bf16_t tmp[8];
  tmp[0] = __float2bfloat16(a.x); tmp[1] = __float2bfloat16(a.y);
  tmp[2] = __float2bfloat16(a.z); tmp[3] = __float2bfloat16(a.w);
  tmp[4] = __float2bfloat16(b.x); tmp[5] = __float2bfloat16(b.y);
  tmp[6] = __float2bfloat16(b.z); tmp[7] = __float2bfloat16(b.w);
  *(uint4*)dst = *(const uint4*)tmp;
}

// ---------------- batched 128^2 projection GEMM (q,k,v via blockIdx.y) -------
// y=0: q = (x@Wq^T + bq)/32 ; y=1: k = x@Wk^T + bk ; y=2: vT = (x@Wv^T+bv)^T
__global__ __launch_bounds__(256, 2)
void gemm_proj(const bf16_t* __restrict__ Abase, const bf16_t* __restrict__ Wbase,
               const float* __restrict__ b0, const float* __restrict__ b1,
               const float* __restrict__ b2, bf16_t* __restrict__ C0,
               bf16_t* __restrict__ C1, bf16_t* __restrict__ C2) {
  __shared__ bf16_t As[128 * 32];
  __shared__ bf16_t Bs[128 * 32];
  const int y = blockIdx.y;
  const bf16_t* A = Abase + (size_t)y * NN * DD;
  const bf16_t* B = Wbase + (size_t)y * DD * DD;
  const float* bias = y == 0 ? b0 : y == 1 ? b1 : b2;
  bf16_t* C = y == 0 ? C0 : y == 1 ? C1 : C2;
  const float scale = y == 0 ? 0.03125f : 1.0f;
  const int ldc = y == 2 ? NN : DD;
  const int K = DD, nbx = DD / 128;

  const int t = threadIdx.x;
  const int nwg = gridDim.x;
  const int bid = (blockIdx.x & 7) * (nwg >> 3) + (blockIdx.x >> 3);
  const int bm = bid / nbx, bn = bid % nbx;
  const int lane = t & 63, wave = t >> 6;
  const int wr = wave >> 1, wc = wave & 1;

  const int c0 = t, c1 = t + 256;
  const bf16_t* ag0 = A + (size_t)(bm * 128 + (c0 >> 2)) * K + (c0 & 3) * 8;
  const bf16_t* ag1 = A + (size_t)(bm * 128 + (c1 >> 2)) * K + (c1 & 3) * 8;
  const bf16_t* bg0 = B + (size_t)(bn * 128 + (c0 >> 2)) * K + (c0 & 3) * 8;
  const bf16_t* bg1 = B + (size_t)(bn * 128 + (c1 >> 2)) * K + (c1 & 3) * 8;
  bf16_t* la0 = As + c0 * 8;
  bf16_t* la1 = As + c1 * 8;
  bf16_t* lb0 = Bs + c0 * 8;
  bf16_t* lb1 = Bs + c1 * 8;

  f32x4 acc[4][4] = {};
  const int fr = lane & 15;
  const int ko = (lane >> 4) * 8;

  for (int kt = 0; kt < K; kt += 32) {
    gload16(ag0 + kt, la0);
    gload16(ag1 + kt, la1);
    gload16(bg0 + kt, lb0);
    gload16(bg1 + kt, lb1);
    __syncthreads();
    bf16x8 af[4], bfv[4];
#pragma unroll
    for (int m = 0; m < 4; m++)
      af[m] = *(const bf16x8*)&As[(wr * 64 + m * 16 + fr) * 32 + ko];
#pragma unroll
    for (int n = 0; n < 4; n++)
      bfv[n] = *(const bf16x8*)&Bs[(wc * 64 + n * 16 + fr) * 32 + ko];
#pragma unroll
    for (int m = 0; m < 4; m++)
#pragma unroll
      for (int n = 0; n < 4; n++)
        acc[m][n] = __builtin_amdgcn_mfma_f32_16x16x32_bf16(af[m], bfv[n], acc[m][n], 0, 0, 0);
    __syncthreads();
  }

  const int rb = (lane >> 4) * 4;
#pragma unroll
  for (int m = 0; m < 4; m++) {
#pragma unroll
    for (int n = 0; n < 4; n++) {
      const int col = bn * 128 + wc * 64 + n * 16 + fr;
      const int row0 = bm * 128 + wr * 64 + m * 16 + rb;
      const float bv = bias[col];
      if (y != 2) {
#pragma unroll
        for (int j = 0; j < 4; j++)
          C[(size_t)(row0 + j) * ldc + col] = __float2bfloat16((acc[m][n][j] + bv) * scale);
      } else {  // transposed store: C[col][row]
        __align__(8) bf16_t tmp[4];
#pragma unroll
        for (int j = 0; j < 4; j++)
          tmp[j] = __float2bfloat16(acc[m][n][j] + bv);
        *(ushort4*)&C[(size_t)col * ldc + row0] = *(const ushort4*)tmp;
      }
    }
  }
}

// ---------------- 256^2 loose-wave NT GEMM (R8 core, proven stable) ----------
// MODE 3: bf16 out = exp(acc), partial row sums -> aux[bn*Mrows + row]
// MODE 4: fp32 atomicAdd(out, acc * aux[row]); blockIdx.y selects K-half.
//   out zeroed beforehand; exactly 2 commutative fp32 adds/element ->
//   deterministic across replays.
template<int MODE>
__global__ __launch_bounds__(512, 2)
void gemm256(const bf16_t* __restrict__ A, int lda,
             const bf16_t* __restrict__ B, int ldb,
             void* __restrict__ Cout, int ldc,
             float* __restrict__ aux, int ksplit, int nkt, int nbx, int Mrows) {
  __shared__ char smem_raw[131072];
  const int t = threadIdx.x;
  const int nwg = gridDim.x;
  const int bid = (blockIdx.x & 7) * (nwg >> 3) + (blockIdx.x >> 3);
  const int bm = bid / nbx, bn = bid % nbx;
  const int lane = t & 63, wave = t >> 6;
  const int wr = wave >> 2, wc = wave & 3;   // 2M x 4N waves
  const int fr = lane & 15, hi = lane >> 4;
  const int k0 = blockIdx.y * ksplit;

  // inverse-swizzled global source (linear gload_lds dest): chunk ^= row&7
  const int cswz = ((t & 7) ^ ((t >> 3) & 7)) * 8;  // elements
  uint32_t offA[2][2], offB[2][2];
#pragma unroll
  for (int h = 0; h < 2; h++)
#pragma unroll
    for (int l = 0; l < 2; l++) {
      const int r = h * 128 + l * 64 + (t >> 3);
      offA[h][l] = (uint32_t)((bm * 256 + r) * lda + k0 + cswz);
      offB[h][l] = (uint32_t)((bn * 256 + r) * ldb + k0 + cswz);
    }

  // swizzled ds_read bases (byte, within buffer), per ks in {0,1}
  const int e = fr & 7;
  const int rowA = (wr * 128 + fr) * 128, rowB = (wc * 64 + fr) * 128;
  const int rdA_k0 = rowA + ((hi ^ e) << 4);
  const int rdA_k1 = rowA + (((hi + 4) ^ e) << 4);
  const int rdB_k0 = rowB + ((hi ^ e) << 4) + 32768;
  const int rdB_k1 = rowB + (((hi + 4) ^ e) << 4) + 32768;

  f32x4 acc[8][4] = {};
  bf16x8 af[4][2], bl[2][2], bh[2][2];

#define STA(buf, h, kt)                                                        \
  gload16(A + offA[h][0] + (size_t)(kt) * 64,                                  \
          smem_raw + (buf) * 65536 + (h) * 16384 + t * 16);                    \
  gload16(A + offA[h][1] + (size_t)(kt) * 64,                                  \
          smem_raw + (buf) * 65536 + (h) * 16384 + 8192 + t * 16);
#define STB(buf, h, kt)                                                        \
  gload16(B + offB[h][0] + (size_t)(kt) * 64,                                  \
          smem_raw + (buf) * 65536 + 32768 + (h) * 16384 + t * 16);            \
  gload16(B + offB[h][1] + (size_t)(kt) * 64,                                  \
          smem_raw + (buf) * 65536 + 32768 + (h) * 16384 + 8192 + t * 16);
#define RDA(buf, mf, ks)                                                       \
  (*(const bf16x8*)(smem_raw + (buf) * 65536 + ((ks) ? rdA_k1 : rdA_k0) +      \
                    (mf) * 2048))
#define RDB(buf, nf, ks)                                                       \
  (*(const bf16x8*)(smem_raw + (buf) * 65536 + ((ks) ? rdB_k1 : rdB_k0) +      \
                    (nf) * 2048))
#define MFMA8(BF, m0, n0)                                                      \
  _Pragma("unroll") for (int m = 0; m < 4; m++)                                \
  _Pragma("unroll") for (int n = 0; n < 2; n++)                                \
  _Pragma("unroll") for (int ks = 0; ks < 2; ks++)                             \
    acc[(m0) + m][(n0) + n] = __builtin_amdgcn_mfma_f32_16x16x32_bf16(         \
        af[m][ks], BF[n][ks], acc[(m0) + m][(n0) + n], 0, 0, 0);

  // prologue: stage tile0 (buf0) fully + B of tile1 (buf1)
  STB(0, 0, 0) STB(0, 1, 0) STA(0, 0, 0) STA(0, 1, 0)
  STB(1, 0, 1) STB(1, 1, 1)
  asm volatile("s_waitcnt vmcnt(4)" ::: "memory");
  __builtin_amdgcn_s_barrier();

  const int nit = nkt >> 1;
  for (int it = 0; it < nit; ++it) {
    const int T1 = 2 * it + 1;
    const int s2 = imin(2 * it + 2, nkt - 1);
    const int s3 = imin(2 * it + 3, nkt - 1);

#define TILEX(buf, S1, S2, S3, S4)                                             \
    /* reads: B (all) + A-lo, consumption order */                             \
    bl[0][0] = RDB(buf, 0, 0); bl[0][1] = RDB(buf, 0, 1);                      \
    bl[1][0] = RDB(buf, 1, 0); bl[1][1] = RDB(buf, 1, 1);                      \
    af[0][0] = RDA(buf, 0, 0); af[0][1] = RDA(buf, 0, 1);                      \
    af[1][0] = RDA(buf, 1, 0); af[1][1] = RDA(buf, 1, 1);                      \
    af[2][0] = RDA(buf, 2, 0); af[2][1] = RDA(buf, 2, 1);                      \
    af[3][0] = RDA(buf, 3, 0); af[3][1] = RDA(buf, 3, 1);                      \
    bh[0][0] = RDB(buf, 2, 0); bh[0][1] = RDB(buf, 2, 1);                      \
    bh[1][0] = RDB(buf, 3, 0); bh[1][1] = RDB(buf, 3, 1);                      \
    __builtin_amdgcn_s_setprio(1);                                             \
    MFMA8(bl, 0, 0)                                                            \
    MFMA8(bh, 0, 2)                                                            \
    __builtin_amdgcn_s_setprio(0);                                             \
    /* B consumed by all waves -> safe to overwrite this buf's B */            \
    __builtin_amdgcn_s_barrier();                                              \
    S1 S2 S3 S4                                                                \
    af[0][0] = RDA(buf, 4, 0); af[0][1] = RDA(buf, 4, 1);                      \
    af[1][0] = RDA(buf, 5, 0); af[1][1] = RDA(buf, 5, 1);                      \
    af[2][0] = RDA(buf, 6, 0); af[2][1] = RDA(buf, 6, 1);                      \
    af[3][0] = RDA(buf, 7, 0); af[3][1] = RDA(buf, 7, 1);                      \
    __builtin_amdgcn_s_setprio(1);                                             \
    MFMA8(bh, 4, 2)                                                            \
    MFMA8(bl, 4, 0)                                                            \
    __builtin_amdgcn_s_setprio(0);                                             \
    asm volatile("s_waitcnt vmcnt(4)" ::: "memory");                           \
    __builtin_amdgcn_s_barrier();

    // tile on buf0 (T0); stages: buf1.A(T1), buf0.B(s2)
    TILEX(0, STA(1, 0, T1), STA(1, 1, T1), STB(0, 0, s2), STB(0, 1, s2))
    // tile on buf1 (T1); stages: buf0.A(s2), buf1.B(s3)
    TILEX(1, STA(0, 0, s2), STA(0, 1, s2), STB(1, 0, s3), STB(1, 1, s3))
#undef TILEX
  }

  // drain stray clamped stages before reusing/leaving LDS
  asm volatile("s_waitcnt vmcnt(0)" ::: "memory");
  __builtin_amdgcn_s_barrier();

  const int gr0 = bm * 256 + wr * 128 + hi * 4;
  const int gc0 = bn * 256 + wc * 64 + fr;

  if (MODE == 3) {
    float* rsum = (float*)smem_raw;
    if (t < 256) rsum[t] = 0.f;
    __syncthreads();
    bf16_t* C = (bf16_t*)Cout;
#pragma unroll
    for (int mf = 0; mf < 8; mf++) {
#pragma unroll
      for (int j = 0; j < 4; j++) {
        float rs = 0.f;
#pragma unroll
        for (int nf = 0; nf < 4; nf++) {
          float e2 = exp2f(acc[mf][nf][j] * 1.44269504088896f);
          bf16_t pb = __float2bfloat16(e2);
          C[(size_t)(gr0 + mf * 16 + j) * ldc + gc0 + nf * 16] = pb;
          rs += __bfloat162float(pb);
        }
        rs += __shfl_xor(rs, 1); rs += __shfl_xor(rs, 2);
        rs += __shfl_xor(rs, 4); rs += __shfl_xor(rs, 8);
        if (fr == 0) atomicAdd(&rsum[wr * 128 + mf * 16 + hi * 4 + j], rs);
      }
    }
    __syncthreads();
    if (t < 256) aux[(size_t)bn * Mrows + bm * 256 + t] = rsum[t];
  } else {  // MODE 4: scaled atomic accumulate into zeroed out; aux = inv_l
    float* C = (float*)Cout;
#pragma unroll
    for (int mf = 0; mf < 8; mf++)
#pragma unroll
      for (int j = 0; j < 4; j++) {
        const int row = gr0 + mf * 16 + j;
        const float s = aux[row];
#pragma unroll
        for (int nf = 0; nf < 4; nf++)
          atomicAdd(&C[(size_t)row * ldc + gc0 + nf * 16], acc[mf][nf][j] * s);
      }
  }
#undef STA
#undef STB
#undef RDA
#undef RDB
#undef MFMA8
}

// ---------------- rowsum partials -> 1/l ----------------
__global__ __launch_bounds__(256) void rowsum_inv_kernel(
    const float* __restrict__ partial, float* __restrict__ inv_l, int nb) {
  const int r = blockIdx.x * 256 + threadIdx.x;
  float s = 0.f;
  for (int b = 0; b < nb; b++) s += partial[(size_t)b * NN + r];
  inv_l[r] = 1.f / s;
}

// ---------------- zero out (float4) ----------------
__global__ __launch_bounds__(256) void zero_kernel(float4* __restrict__ p) {
  p[(size_t)blockIdx.x * 256 + threadIdx.x] = make_float4(0.f, 0.f, 0.f, 0.f);
}

extern "C" void kernel_launch(void* const* d_in, const int* in_sizes, int n_in,
                              void* d_out, int out_size, void* d_ws, size_t ws_size,
                              hipStream_t stream) {
  const float* queries = (const float*)d_in[0];
  const float* key_in  = (const float*)d_in[1];
  const float* values  = (const float*)d_in[2];
  const float* Wq = (const float*)d_in[3];
  const float* bq = (const float*)d_in[4];
  const float* Wk = (const float*)d_in[5];
  const float* bk = (const float*)d_in[6];
  const float* Wv = (const float*)d_in[7];
  const float* bv = (const float*)d_in[8];
  float* out = (float*)d_out;
  char* ws = (char*)d_ws;

  const size_t MB = 1024 * 1024;
  bf16_t* qb = (bf16_t*)(ws);                 // 16 MiB
  bf16_t* kb = (bf16_t*)(ws + 16 * MB);       // 16 MiB
  bf16_t* vT = (bf16_t*)(ws + 32 * MB);       // [1024][8192], 16 MiB
  bf16_t* P  = (bf16_t*)(ws + 48 * MB);       // [8192][8192] bf16, 128 MiB
  float* partial = (float*)(ws + 176 * MB);   // [32][8192] fp32, 1 MiB
  float* inv_l   = (float*)(ws + 177 * MB);   // 32 KiB
  // projection-phase staging overlaps the P region (dead until QK^T):
  bf16_t* x3 = (bf16_t*)(ws + 48 * MB);       // 3 x 16 MiB bf16 inputs
  bf16_t* w3 = (bf16_t*)(ws + 96 * MB);       // 3 x 2 MiB bf16 weights

  const int nd8 = NN * DD / 8, dd8 = DD * DD / 8;

  // 1) cast all inputs+weights to bf16 (single launch)
  cast6_kernel<<<(3 * nd8 + 3 * dd8) / 256, 256, 0, stream>>>(
      queries, key_in, values, Wq, Wk, Wv, x3, w3);
  // 2) all three projections (single launch, y selects q/k/v)
  gemm_proj<<<dim3((NN / 128) * (DD / 128), 3), 256, 0, stream>>>(
      x3, w3, bq, bk, bv, qb, kb, vT);
  // 3) fused QK^T -> exp -> bf16 P (+ partial row sums)
  gemm256<3><<<dim3((NN / 256) * (NN / 256)), 512, 0, stream>>>(
      qb, DD, kb, DD, P, NN, partial, 0, DD / 64, NN / 256, NN);
  // 4) l[row] -> 1/l ; zero the output accumulator
  rowsum_inv_kernel<<<NN / 256, 256, 0, stream>>>(partial, inv_l, NN / 256);
  zero_kernel<<<NN * DD / 4 / 256, 256, 0, stream>>>((float4*)out);
  // 5) PV split-K=2, scaled atomic accumulate into out
  gemm256<4><<<dim3((NN / 256) * (DD / 256), 2), 512, 0, stream>>>(
      P, NN, vT, NN, out, DD, inv_l, NN / 2, NN / 2 / 64, DD / 256, NN);
}